// Round 7
// baseline (209.455 us; speedup 1.0000x reference)
//
#include <hip/hip_runtime.h>
#include <cstdint>

#define NN 512
#define EE 64
#define HIDD 256
#define OUTD 32
#define L2E 1.4426950408889634f

typedef __bf16 bf16x8 __attribute__((ext_vector_type(8)));
typedef float f32x4 __attribute__((ext_vector_type(4)));

// -------- device-global scratch (fully rewritten every call; deterministic) --------
__device__ float g_WhsT[HIDD*EE];      // W_hs transposed [k][e]
__device__ float g_M2T[EE*EE];         // qk-matrix [c][e], log2e*scale folded
__device__ float g_cvec[EE];
__device__ uint4 g_Ag2[4096];          // bf16 A-frags, gate-scaled; idx = (mh*4+kh)*64 + lane
__device__ float g_biasI[256];         // [e*4 + gate], gate-scaled
__device__ float g_embW[EE*4];         // per-e embed (a,b,bias,0)
__device__ float g_Wtot[OUTD*EE];      // W_o @ W_out @ Wv_comb
__device__ float g_btot[OUTD];

__device__ __forceinline__ float ex2(float x){ return __builtin_amdgcn_exp2f(x); }
__device__ __forceinline__ float rcp_(float x){ return __builtin_amdgcn_rcpf(x); }

// LSTM elementwise in base-2 domain: g4 = (yi, yf, yg, yo) with yi,yf,yo = -L2E*pre,
// yg = -2*L2E*pre (scales folded into weights+bias). Returns h.
__device__ __forceinline__ float lstm_h(f32x4 g4, float c) {
    float si = rcp_(1.f + ex2(g4[0]));
    float sf = rcp_(1.f + ex2(g4[1]));
    float so = rcp_(1.f + ex2(g4[3]));
    float tg = fmaf(2.f, rcp_(1.f + ex2(g4[2])), -1.f);          // tanh(pre_g)
    float cn = fmaf(sf, c, si * tg);
    float tc = fmaf(2.f, rcp_(1.f + ex2(-2.f*L2E*cn)), -1.f);    // tanh(cn)
    return so * tc;
}

// ---------------- prepW: all weight packing in ONE launch (7 blocks) --------
__global__ __launch_bounds__(256) void prepW(
    const float* __restrict__ W_ih, const float* __restrict__ b_ih,
    const float* __restrict__ W_hh, const float* __restrict__ b_hh,
    const float* __restrict__ Wq, const float* __restrict__ Wk, const float* __restrict__ Wv,
    const float* __restrict__ W_in, const float* __restrict__ W_hs,
    const float* __restrict__ W_s, const float* __restrict__ b_s,
    const float* __restrict__ W_v, const float* __restrict__ b_v,
    const float* __restrict__ b_in, const float* __restrict__ W_out,
    const float* __restrict__ b_out, const float* __restrict__ W_o,
    const float* __restrict__ b_o)
{
    const int blk = blockIdx.x, tid = threadIdx.x;
    if (blk < 4) {
        // A-frags: frag (mh 0..15, kh 0..3). lane: row'=l&15 -> e=4mh+(row'>>2), gate=row'&3;
        // k = kh*32 + (l>>4)*8 + j
#pragma unroll
        for (int ii = 0; ii < 4; ++ii) {
            int idx = blk*1024 + ii*256 + tid;
            int mh = idx >> 8, kh = (idx >> 6) & 3, lane = idx & 63;
            int e = 4*mh + ((lane & 15) >> 2);
            int gate = lane & 3;
            int o = gate*64 + e;
            int kb = kh*32 + (lane >> 4)*8;
            float sc = (gate == 2) ? (-2.f*L2E) : (-L2E);
            bf16x8 vv;
#pragma unroll
            for (int j = 0; j < 8; ++j) {
                int k = kb + j;
                float raw = (k < 64) ? W_ih[o*64 + k] : W_hh[o*64 + (k - 64)];
                vv[j] = (__bf16)(sc * raw);
            }
            g_Ag2[idx] = __builtin_bit_cast(uint4, vv);
        }
    } else if (blk == 4) {
        __shared__ float T[64][65];
        {
            int e = tid >> 2, gate = tid & 3, o = gate*64 + e;
            float sc = (gate == 2) ? (-2.f*L2E) : (-L2E);
            g_biasI[tid] = sc * (b_ih[o] + b_hh[o]);
        }
        if (tid < 64) {
            int e = tid;
            if (e < 32) {
                g_embW[e*4+0] = W_s[e*2]; g_embW[e*4+1] = W_s[e*2+1]; g_embW[e*4+2] = b_s[e];
            } else {
                g_embW[e*4+0] = 4.f*W_v[(e-32)*2]; g_embW[e*4+1] = 4.f*W_v[(e-32)*2+1]; g_embW[e*4+2] = b_v[e-32];
            }
            g_embW[e*4+3] = 0.f;
        }
        // coalesced LDS-tiled transpose of W_hs [64][256] -> g_WhsT [256][64]
        for (int kt = 0; kt < 4; ++kt) {
            __syncthreads();
#pragma unroll
            for (int i = 0; i < 16; ++i) {
                int row = i*4 + (tid >> 6);
                int col = tid & 63;
                T[col][row] = W_hs[row*256 + kt*64 + col];
            }
            __syncthreads();
#pragma unroll
            for (int i = 0; i < 16; ++i) {
                int krow = i*4 + (tid >> 6);
                int e = tid & 63;
                g_WhsT[(kt*64 + krow)*64 + e] = T[krow][e];
            }
        }
    } else if (blk == 5) {
        // q/k combined projections locally, then M2T = (L2E/8) * Wkc^T Wqc and cvec
        __shared__ float WqcL[4096];
        __shared__ float WkcL[4096];
        for (int idx = tid; idx < 4096; idx += 256) {
            int a = idx >> 6, c = idx & 63;
            float s0 = 0.f, s1 = 0.f;
            for (int m = 0; m < 64; ++m) {
                s0 = fmaf(W_in[a*64 + m],        Wq[m*64 + c], s0);
                s1 = fmaf(W_in[4096 + a*64 + m], Wk[m*64 + c], s1);
            }
            WqcL[idx] = s0; WkcL[idx] = s1;
        }
        __syncthreads();
        for (int idx = tid; idx < 4096; idx += 256) {
            int c = idx >> 6, e = idx & 63;
            float s = 0.f;
            for (int a = 0; a < 64; ++a) s = fmaf(WkcL[a*64 + e], WqcL[a*64 + c], s);
            g_M2T[idx] = s * (L2E * 0.125f);
        }
        if (tid < 64) {
            float s = 0.f;
            for (int a = 0; a < 64; ++a) s = fmaf(WkcL[a*64 + tid], b_in[a], s);
            g_cvec[tid] = s * (L2E * 0.125f);
        }
    } else {
        // v combined projection locally, then Wtot = W_o @ W_out @ Wvc, btot
        __shared__ float WvcL[4096];
        __shared__ float Wtmp[4096];
        __shared__ float bb[64];
        for (int idx = tid; idx < 4096; idx += 256) {
            int a = idx >> 6, c = idx & 63;
            float s = 0.f;
            for (int m = 0; m < 64; ++m) s = fmaf(W_in[2*4096 + a*64 + m], Wv[m*64 + c], s);
            WvcL[idx] = s;
        }
        __syncthreads();
        for (int idx = tid; idx < 4096; idx += 256) {
            int i = idx >> 6, jj = idx & 63;
            float s = 0.f;
            for (int k = 0; k < 64; ++k) s = fmaf(W_out[i*64 + k], WvcL[k*64 + jj], s);
            Wtmp[idx] = s;
        }
        if (tid < 64) {
            float s = 0.f;
            for (int k = 0; k < 64; ++k) s = fmaf(W_out[tid*64 + k], b_in[128 + k], s);
            bb[tid] = s + b_out[tid];
        }
        __syncthreads();
        for (int idx = tid; idx < OUTD*64; idx += 256) {
            int o = idx >> 6, jj = idx & 63;
            float s = 0.f;
            for (int i = 0; i < 64; ++i) s = fmaf(W_o[o*64 + i], Wtmp[i*64 + jj], s);
            g_Wtot[idx] = s;
        }
        if (tid < OUTD) {
            float s = 0.f;
            for (int i = 0; i < 64; ++i) s = fmaf(W_o[tid*64 + i], bb[i], s);
            g_btot[tid] = s + b_o[tid];
        }
    }
}

// ---------------- row kernel: 512 blocks x 256 thr (4 waves); wave owns full
// softmax rows (32 pairs x all 64 e per strip, 4 strips). No barriers in loop.
__global__ __launch_bounds__(256, 2) void row_kernel(
    const float* __restrict__ hidden, const float* __restrict__ b_hs,
    const float* __restrict__ obs1, const float* __restrict__ obs2,
    const float* __restrict__ h0, const float* __restrict__ c0,
    float* __restrict__ out)
{
    __shared__ __align__(16) uint4 WgL[4096];     // 64KB gate-weight A-frags
    __shared__ float2 obs1L[NN];                  // 4KB
    __shared__ float2 obs2L[NN];                  // 4KB
    __shared__ __align__(16) float biasL[256];    // 1KB
    __shared__ __align__(16) float4 embL[64];     // 1KB
    __shared__ float hid[HIDD];
    __shared__ float part[4][64];
    __shared__ float hsL[64], qkL[64];
    __shared__ float ctxW[4][64];
    __shared__ float mW[4], lW[4];
    __shared__ float ctxE[64];

    const int b = blockIdx.x, tid = threadIdx.x;
    const int w = tid >> 6, l = tid & 63;
    const int q = l >> 4, r = l & 15;
    const float* h0r = h0 + (size_t)b*NN*EE;
    const float* c0r = c0 + (size_t)b*NN*EE;

    // ---- stage gate weights (64KB) direct-to-LDS, linear both sides ----
#pragma unroll
    for (int i = 0; i < 16; ++i) {
        int off = (i*256 + tid) * 16;
        __builtin_amdgcn_global_load_lds(
            (const __attribute__((address_space(1))) void*)((const char*)g_Ag2 + off),
            (__attribute__((address_space(3))) void*)((char*)WgL + off), 16, 0, 0);
    }
    obs2L[tid]       = ((const float2*)obs2)[tid];
    obs2L[tid + 256] = ((const float2*)obs2)[tid + 256];
    obs1L[tid]       = ((const float2*)obs1)[tid];
    obs1L[tid + 256] = ((const float2*)obs1)[tid + 256];
    biasL[tid] = g_biasI[tid];
    if (tid < 64) embL[tid] = *(const float4*)(g_embW + tid*4);
    hid[tid] = hidden[b*HIDD + tid];
    __syncthreads();

    // ---- hs = W_hs @ hidden + b_hs ----
    {
        float s = 0.f;
#pragma unroll 8
        for (int k2 = 0; k2 < 64; ++k2) {
            int kk = w*64 + k2;
            s = fmaf(g_WhsT[kk*64 + l], hid[kk], s);
        }
        part[w][l] = s;
    }
    __syncthreads();
    if (tid < 64) hsL[tid] = part[0][tid] + part[1][tid] + part[2][tid] + part[3][tid] + b_hs[tid];
    __syncthreads();
    // ---- qk = M2T^T @ hs + cvec (log2e-scaled) ----
    {
        float s = 0.f;
#pragma unroll
        for (int k2 = 0; k2 < 16; ++k2) {
            int kk = w*16 + k2;
            s = fmaf(g_M2T[kk*64 + l], hsL[kk], s);
        }
        part[w][l] = s;
    }
    __syncthreads();
    if (tid < 64) qkL[tid] = part[0][tid] + part[1][tid] + part[2][tid] + part[3][tid] + g_cvec[tid];
    __syncthreads();

    const float ob2x = obs2L[b].x, ob2y = obs2L[b].y;
    const float ob1x = obs1L[b].x, ob1y = obs1L[b].y;
    const float velbx = ob2x - ob1x, velby = ob2y - ob1y;

    float m_run = -__builtin_inff(), l_run = 0.f;
    float ctxa[16];
#pragma unroll
    for (int i = 0; i < 16; ++i) ctxa[i] = 0.f;

    // ---- main loop: 4 strips of 32 pairs per wave; NO barriers ----
    for (int s = 0; s < 4; ++s) {
        const int base = s*128 + w*32;
        const int p0 = base + r, p1 = base + 16 + r;

        // H rows for B-frags kh 2,3 (row-contiguous 32B chunks per lane)
        const float* hp0 = h0r + p0*EE + q*8;
        const float* hp1 = h0r + p1*EE + q*8;
        f32x4 hA0 = *(const f32x4*)(hp0);      f32x4 hA1 = *(const f32x4*)(hp0 + 4);
        f32x4 hB0 = *(const f32x4*)(hp0 + 32); f32x4 hB1 = *(const f32x4*)(hp0 + 36);
        f32x4 hC0 = *(const f32x4*)(hp1);      f32x4 hC1 = *(const f32x4*)(hp1 + 4);
        f32x4 hD0 = *(const f32x4*)(hp1 + 32); f32x4 hD1 = *(const f32x4*)(hp1 + 36);

        // C values (stride-4 within own row; rows fully consumed by this wave)
        float cb0[16], cb1[16];
        const float* cp0 = c0r + p0*EE + q;
        const float* cp1 = c0r + p1*EE + q;
#pragma unroll
        for (int mh = 0; mh < 16; ++mh) { cb0[mh] = cp0[4*mh]; cb1[mh] = cp1[4*mh]; }

        // in-register embed -> B-frags kh 0 (spatial) and 1 (velocity)
        float2 o2a = obs2L[p0], o1a = obs1L[p0];
        float2 o2b = obs2L[p1], o1b = obs1L[p1];
        float sa0 = o2a.x - ob2x, sa1 = o2a.y - ob2y;
        float va0 = (o2a.x - o1a.x) - velbx, va1 = (o2a.y - o1a.y) - velby;
        float sb0 = o2b.x - ob2x, sb1 = o2b.y - ob2y;
        float vb0 = (o2b.x - o1b.x) - velbx, vb1 = (o2b.y - o1b.y) - velby;
        bf16x8 Bf0[4], Bf1[4];
#pragma unroll
        for (int i = 0; i < 8; ++i) {
            float4 e0 = embL[q*8 + i];        // e = q*8+i  (spatial)
            float4 e1 = embL[32 + q*8 + i];   // e = 32+q*8+i (velocity)
            Bf0[0][i] = (__bf16)fmaxf(fmaf(e0.x, sa0, fmaf(e0.y, sa1, e0.z)), 0.f);
            Bf0[1][i] = (__bf16)fmaxf(fmaf(e1.x, va0, fmaf(e1.y, va1, e1.z)), 0.f);
            Bf1[0][i] = (__bf16)fmaxf(fmaf(e0.x, sb0, fmaf(e0.y, sb1, e0.z)), 0.f);
            Bf1[1][i] = (__bf16)fmaxf(fmaf(e1.x, vb0, fmaf(e1.y, vb1, e1.z)), 0.f);
        }
#pragma unroll
        for (int i = 0; i < 4; ++i) {
            Bf0[2][i] = (__bf16)hA0[i]; Bf0[2][4+i] = (__bf16)hA1[i];
            Bf0[3][i] = (__bf16)hB0[i]; Bf0[3][4+i] = (__bf16)hB1[i];
            Bf1[2][i] = (__bf16)hC0[i]; Bf1[2][4+i] = (__bf16)hC1[i];
            Bf1[3][i] = (__bf16)hD0[i]; Bf1[3][4+i] = (__bf16)hD1[i];
        }

        float Eev0[16], Eev1[16];
        float sp0 = 0.f, sp1 = 0.f;
        const bool diagw = (b >= base) && (b < base + 32);

#pragma unroll
        for (int mh = 0; mh < 16; ++mh) {
            f32x4 bias4 = *(const f32x4*)(biasL + (4*mh + q)*4);   // broadcast b128
            float qke = qkL[4*mh + q];
            f32x4 a0 = bias4, a1 = bias4;
#pragma unroll
            for (int kh = 0; kh < 4; ++kh) {
                bf16x8 Af = __builtin_bit_cast(bf16x8, WgL[(mh*4 + kh)*64 + l]);
                a0 = __builtin_amdgcn_mfma_f32_16x16x32_bf16(Af, Bf0[kh], a0, 0, 0, 0);
                a1 = __builtin_amdgcn_mfma_f32_16x16x32_bf16(Af, Bf1[kh], a1, 0, 0, 0);
            }
            float h_0 = lstm_h(a0, cb0[mh]);
            float h_1 = lstm_h(a1, cb1[mh]);
            if (diagw) {                       // wave-uniform branch; 1 strip per row
                float hsv = hsL[4*mh + q];
                if (p0 == b) h_0 = hsv;
                if (p1 == b) h_1 = hsv;
            }
            Eev0[mh] = h_0; Eev1[mh] = h_1;
            sp0 = fmaf(qke, h_0, sp0);
            sp1 = fmaf(qke, h_1, sp1);
        }
        // intra-wave score reduce over q (lanes 16,32 apart share the same pair)
        sp0 += __shfl_xor(sp0, 16, 64); sp0 += __shfl_xor(sp0, 32, 64);
        sp1 += __shfl_xor(sp1, 16, 64); sp1 += __shfl_xor(sp1, 32, 64);
        // strip max over the 16 r's
        float tm = fmaxf(sp0, sp1);
        tm = fmaxf(tm, __shfl_xor(tm, 1, 64));
        tm = fmaxf(tm, __shfl_xor(tm, 2, 64));
        tm = fmaxf(tm, __shfl_xor(tm, 4, 64));
        tm = fmaxf(tm, __shfl_xor(tm, 8, 64));
        float m_new = fmaxf(m_run, tm);
        float corr = ex2(m_run - m_new);       // first strip: exp2(-inf)=0
        float wp0 = ex2(sp0 - m_new), wp1 = ex2(sp1 - m_new);
        l_run = fmaf(l_run, corr, wp0 + wp1);
        m_run = m_new;
#pragma unroll
        for (int mh = 0; mh < 16; ++mh)
            ctxa[mh] = fmaf(wp1, Eev1[mh], fmaf(wp0, Eev0[mh], ctxa[mh]*corr));
    }

    // ---- epilogue: per-wave reduce, 4-way merge, output projection ----
    float lred = l_run;
    lred += __shfl_xor(lred, 1, 64); lred += __shfl_xor(lred, 2, 64);
    lred += __shfl_xor(lred, 4, 64); lred += __shfl_xor(lred, 8, 64);
#pragma unroll
    for (int mh = 0; mh < 16; ++mh) {
        float v = ctxa[mh];
        v += __shfl_xor(v, 1, 64); v += __shfl_xor(v, 2, 64);
        v += __shfl_xor(v, 4, 64); v += __shfl_xor(v, 8, 64);
        if (r == 0) ctxW[w][4*mh + q] = v;     // lanes 0,16,32,48 write e=4mh+q
    }
    if (l == 0) { mW[w] = m_run; lW[w] = lred; }
    __syncthreads();
    if (tid < 64) {
        float M = fmaxf(fmaxf(mW[0], mW[1]), fmaxf(mW[2], mW[3]));
        float f0 = ex2(mW[0] - M), f1 = ex2(mW[1] - M);
        float f2 = ex2(mW[2] - M), f3 = ex2(mW[3] - M);
        float csum = ctxW[0][tid]*f0 + ctxW[1][tid]*f1 + ctxW[2][tid]*f2 + ctxW[3][tid]*f3;
        float lsum = lW[0]*f0 + lW[1]*f1 + lW[2]*f2 + lW[3]*f3;
        ctxE[tid] = csum * rcp_(lsum);
    }
    __syncthreads();
    if (tid < OUTD) {
        float sAcc = g_btot[tid];
        const float* wr2 = g_Wtot + tid*64;
        for (int k = 0; k < 64; ++k) sAcc = fmaf(wr2[k], ctxE[k], sAcc);
        out[b*OUTD + tid] = sAcc;
    }
}

extern "C" void kernel_launch(void* const* d_in, const int* in_sizes, int n_in,
                              void* d_out, int out_size, void* d_ws, size_t ws_size,
                              hipStream_t stream) {
    const float* hidden = (const float*)d_in[0];
    const float* obs1   = (const float*)d_in[1];
    const float* obs2   = (const float*)d_in[2];
    const float* h0     = (const float*)d_in[3];
    const float* c0     = (const float*)d_in[4];
    const float* W_s    = (const float*)d_in[5];
    const float* b_s    = (const float*)d_in[6];
    const float* W_v    = (const float*)d_in[7];
    const float* b_v    = (const float*)d_in[8];
    const float* W_hs   = (const float*)d_in[9];
    const float* b_hs   = (const float*)d_in[10];
    const float* W_ih   = (const float*)d_in[11];
    const float* b_ih   = (const float*)d_in[12];
    const float* W_hh   = (const float*)d_in[13];
    const float* b_hh   = (const float*)d_in[14];
    const float* Wq     = (const float*)d_in[15];
    const float* Wk     = (const float*)d_in[16];
    const float* Wv     = (const float*)d_in[17];
    const float* W_in   = (const float*)d_in[18];
    const float* b_in   = (const float*)d_in[19];
    const float* W_out  = (const float*)d_in[20];
    const float* b_out  = (const float*)d_in[21];
    const float* W_o    = (const float*)d_in[22];
    const float* b_o    = (const float*)d_in[23];

    prepW<<<dim3(7), dim3(256), 0, stream>>>(
        W_ih, b_ih, W_hh, b_hh, Wq, Wk, Wv, W_in, W_hs, W_s, b_s, W_v, b_v,
        b_in, W_out, b_out, W_o, b_o);
    row_kernel<<<dim3(NN), dim3(256), 0, stream>>>(
        hidden, b_hs, obs1, obs2, h0, c0, (float*)d_out);
}

// Round 8
// 97.682 us; speedup vs baseline: 2.1443x; 2.1443x over previous
//
#include <hip/hip_runtime.h>
#include <cstdint>

#define NN 512
#define EE 64
#define HIDD 256
#define OUTD 32
#define L2E 1.4426950408889634f

typedef __bf16 bf16x8 __attribute__((ext_vector_type(8)));
typedef __bf16 bf16x4 __attribute__((ext_vector_type(4)));
typedef float f32x4 __attribute__((ext_vector_type(4)));
typedef float f32x2 __attribute__((ext_vector_type(2)));

// -------- device-global scratch (fully rewritten every call; deterministic) --------
__device__ float g_WhsT[HIDD*EE];      // W_hs transposed [k][e]
__device__ float g_M2T[EE*EE];         // qk-matrix [c][e], log2e*scale folded
__device__ float g_cvec[EE];
__device__ uint4 g_Ag2[4096];          // bf16 A-frags, gate-scaled; idx = w:3|mh:1|kh:2|lane:6
__device__ float g_biasI[256];         // [e*4 + gate], gate-scaled
__device__ float g_embW[EE*4];         // per-e embed (a,b,bias,0)
__device__ float g_Wtot[OUTD*EE];      // W_o @ W_out @ Wv_comb
__device__ float g_btot[OUTD];

__device__ __forceinline__ float ex2(float x){ return __builtin_amdgcn_exp2f(x); }
__device__ __forceinline__ float rcp_(float x){ return __builtin_amdgcn_rcpf(x); }

// ---------------- prepW: all packing, 12 parallel blocks ----------------
__global__ __launch_bounds__(256) void prepW(
    const float* __restrict__ W_ih, const float* __restrict__ b_ih,
    const float* __restrict__ W_hh, const float* __restrict__ b_hh,
    const float* __restrict__ Wq, const float* __restrict__ Wk, const float* __restrict__ Wv,
    const float* __restrict__ W_in, const float* __restrict__ W_hs,
    const float* __restrict__ W_s, const float* __restrict__ b_s,
    const float* __restrict__ W_v, const float* __restrict__ b_v,
    const float* __restrict__ b_in, const float* __restrict__ W_out,
    const float* __restrict__ b_out, const float* __restrict__ W_o,
    const float* __restrict__ b_o)
{
    const int blk = blockIdx.x, tid = threadIdx.x;
    if (blk < 8) {
        // A-frags: wave w owns e in [8w,8w+8); e = 8w + 2*qq + mh; lane m = 4*qq+gate
#pragma unroll
        for (int ii = 0; ii < 2; ++ii) {
            int idx = blk*512 + ii*256 + tid;
            int w = idx >> 9, mh = (idx >> 8) & 1, kh = (idx >> 6) & 3, lane = idx & 63;
            int m = lane & 15, qq = m >> 2, gate = m & 3;
            int e = 8*w + 2*qq + mh;
            int o = gate*64 + e;
            int kb = kh*32 + (lane >> 4)*8;
            float sc = (gate == 2) ? (-2.f*L2E) : (-L2E);
            bf16x8 vv;
#pragma unroll
            for (int j = 0; j < 8; ++j) {
                int k = kb + j;
                float raw = (k < 64) ? W_ih[o*64 + k] : W_hh[o*64 + (k - 64)];
                vv[j] = (__bf16)(sc * raw);
            }
            g_Ag2[idx] = __builtin_bit_cast(uint4, vv);
        }
    } else if (blk == 8) {
        {
            int e = tid >> 2, gate = tid & 3, o = gate*64 + e;
            float sc = (gate == 2) ? (-2.f*L2E) : (-L2E);
            g_biasI[tid] = sc * (b_ih[o] + b_hh[o]);
        }
        if (tid < 64) {
            int e = tid;
            if (e < 32) {
                g_embW[e*4+0] = W_s[e*2]; g_embW[e*4+1] = W_s[e*2+1]; g_embW[e*4+2] = b_s[e];
            } else {
                g_embW[e*4+0] = 4.f*W_v[(e-32)*2]; g_embW[e*4+1] = 4.f*W_v[(e-32)*2+1]; g_embW[e*4+2] = b_v[e-32];
            }
            g_embW[e*4+3] = 0.f;
        }
    } else if (blk == 9) {
        // coalesced LDS-tiled transpose W_hs [64][256] -> g_WhsT [256][64]
        __shared__ float T[64][65];
        for (int kt = 0; kt < 4; ++kt) {
            __syncthreads();
#pragma unroll
            for (int i = 0; i < 16; ++i) {
                int row = i*4 + (tid >> 6);
                int col = tid & 63;
                T[col][row] = W_hs[row*256 + kt*64 + col];
            }
            __syncthreads();
#pragma unroll
            for (int i = 0; i < 16; ++i) {
                int krow = i*4 + (tid >> 6);
                int e = tid & 63;
                g_WhsT[(kt*64 + krow)*64 + e] = T[krow][e];
            }
        }
    } else if (blk == 10) {
        // M2T = (L2E/8) * Wkc^T Wqc; cvec
        __shared__ float WqcL[4096];
        __shared__ float WkcL[4096];
        for (int idx = tid; idx < 4096; idx += 256) {
            int a = idx >> 6, c = idx & 63;
            float s0 = 0.f, s1 = 0.f;
            for (int m = 0; m < 64; ++m) {
                s0 = fmaf(W_in[a*64 + m],        Wq[m*64 + c], s0);
                s1 = fmaf(W_in[4096 + a*64 + m], Wk[m*64 + c], s1);
            }
            WqcL[idx] = s0; WkcL[idx] = s1;
        }
        __syncthreads();
        for (int idx = tid; idx < 4096; idx += 256) {
            int c = idx >> 6, e = idx & 63;
            float s = 0.f;
            for (int a = 0; a < 64; ++a) s = fmaf(WkcL[a*64 + e], WqcL[a*64 + c], s);
            g_M2T[idx] = s * (L2E * 0.125f);
        }
        if (tid < 64) {
            float s = 0.f;
            for (int a = 0; a < 64; ++a) s = fmaf(WkcL[a*64 + tid], b_in[a], s);
            g_cvec[tid] = s * (L2E * 0.125f);
        }
    } else {
        // Wtot = W_o @ W_out @ Wvc; btot
        __shared__ float WvcL[4096];
        __shared__ float Wtmp[4096];
        __shared__ float bb[64];
        for (int idx = tid; idx < 4096; idx += 256) {
            int a = idx >> 6, c = idx & 63;
            float s = 0.f;
            for (int m = 0; m < 64; ++m) s = fmaf(W_in[2*4096 + a*64 + m], Wv[m*64 + c], s);
            WvcL[idx] = s;
        }
        __syncthreads();
        for (int idx = tid; idx < 4096; idx += 256) {
            int i = idx >> 6, jj = idx & 63;
            float s = 0.f;
            for (int k = 0; k < 64; ++k) s = fmaf(W_out[i*64 + k], WvcL[k*64 + jj], s);
            Wtmp[idx] = s;
        }
        if (tid < 64) {
            float s = 0.f;
            for (int k = 0; k < 64; ++k) s = fmaf(W_out[tid*64 + k], b_in[128 + k], s);
            bb[tid] = s + b_out[tid];
        }
        __syncthreads();
        for (int idx = tid; idx < OUTD*64; idx += 256) {
            int o = idx >> 6, jj = idx & 63;
            float s = 0.f;
            for (int i = 0; i < 64; ++i) s = fmaf(W_o[o*64 + i], Wtmp[i*64 + jj], s);
            g_Wtot[idx] = s;
        }
        if (tid < OUTD) {
            float s = 0.f;
            for (int i = 0; i < 64; ++i) s = fmaf(W_o[tid*64 + i], bb[i], s);
            g_btot[tid] = s + b_o[tid];
        }
    }
}

// ---------------- row kernel: 512 blocks x 512 thr, full row, 16 tiles of 32,
// triple-buffered H/C, double-buffered Xe/spart, ONE barrier per tile ----------
__global__ __launch_bounds__(512, 4) void row_kernel(
    const float* __restrict__ hidden, const float* __restrict__ b_hs,
    const float* __restrict__ obs1, const float* __restrict__ obs2,
    const float* __restrict__ h0, const float* __restrict__ c0,
    float* __restrict__ out)
{
    __shared__ __align__(16) float Hs[3][32*64];          // 24KB, swizzled 256B rows
    __shared__ __align__(16) float Cs[3][32*64];          // 24KB
    __shared__ __align__(16) unsigned short Xe[2][32*64]; // 8KB bf16, swizzled 128B rows
    __shared__ float spart[2][8][32];                     // 2KB
    __shared__ float2 obs1L[NN], obs2L[NN];               // 8KB
    __shared__ float hid[HIDD];
    __shared__ float part[8][64];
    __shared__ float hsL[64], qkL[64];
    __shared__ float ctxE[64];

    const int b = blockIdx.x, tid = threadIdx.x;
    const int w = tid >> 6, l = tid & 63;
    const int q = l >> 4, r = l & 15;
    const int ebase0 = 8*w + 2*q;
    const float* h0r = h0 + (size_t)b*NN*EE;
    const float* c0r = c0 + (size_t)b*NN*EE;

    // ---- staging: 1 global_load_lds (16B) per thread per buffer, pre-swizzled src ----
    auto stageT = [&](const float* gsrc, float* lbuf) {
        const int row = tid >> 4;                  // 0..31
        const int cb  = (tid & 15) * 16;
        const char* g = (const char*)gsrc + row*256 + (cb ^ ((row & 15) << 4));
        char* lp = (char*)lbuf + tid*16;
        __builtin_amdgcn_global_load_lds(
            (const __attribute__((address_space(1))) void*)g,
            (__attribute__((address_space(3))) void*)lp, 16, 0, 0);
    };

    // ---- register hoists ----
    uint4 Afr[2][4];
#pragma unroll
    for (int mh = 0; mh < 2; ++mh)
#pragma unroll
        for (int kh = 0; kh < 4; ++kh)
            Afr[mh][kh] = g_Ag2[w*512 + mh*256 + kh*64 + l];
    f32x4 biasv[2];
#pragma unroll
    for (int mh = 0; mh < 2; ++mh) {
        float4 t4 = *(const float4*)(g_biasI + (ebase0 + mh)*4);
        biasv[mh][0]=t4.x; biasv[mh][1]=t4.y; biasv[mh][2]=t4.z; biasv[mh][3]=t4.w;
    }
    float eA[4], eB[4], eC[4];
    {
        const int e0 = (tid & 15)*4;
#pragma unroll
        for (int i = 0; i < 4; ++i) {
            eA[i] = g_embW[(e0+i)*4+0]; eB[i] = g_embW[(e0+i)*4+1]; eC[i] = g_embW[(e0+i)*4+2];
        }
    }

    // ---- embed tile: thread = (p = tid>>4, e-quad tid&15), from LDS obs ----
    const float ob2x = obs2[b*2], ob2y = obs2[b*2+1];
    const float ob1x = obs1[b*2], ob1y = obs1[b*2+1];
    const float velbx = ob2x - ob1x, velby = ob2y - ob1y;
    auto embedW = [&](int jb, unsigned short* xe) {
        const int p = tid >> 4;
        const float2 o2 = obs2L[jb + p];
        const float2 o1 = obs1L[jb + p];
        const float u0s = o2.x - ob2x, u1s = o2.y - ob2y;
        const float u0v = (o2.x - o1.x) - velbx, u1v = (o2.y - o1.y) - velby;
        const bool sph = ((tid & 15) < 8);
        const float u0 = sph ? u0s : u0v, u1 = sph ? u1s : u1v;
        bf16x4 pk;
#pragma unroll
        for (int i = 0; i < 4; ++i)
            pk[i] = (__bf16)fmaxf(fmaf(eA[i], u0, fmaf(eB[i], u1, eC[i])), 0.f);
        *(bf16x4*)((char*)xe + p*128 + (((tid & 15)*8) ^ ((p & 7) << 4))) = pk;
    };

    // ---- prologue: issue stage(0),stage(1); obs/hid -> LDS; hs/qk; embed(0) ----
    stageT(h0r, Hs[0]);
    stageT(c0r, Cs[0]);
    stageT(h0r + 32*EE, Hs[1]);
    stageT(c0r + 32*EE, Cs[1]);
    obs2L[tid] = ((const float2*)obs2)[tid];
    obs1L[tid] = ((const float2*)obs1)[tid];
    if (tid < HIDD) hid[tid] = hidden[b*HIDD + tid];
    asm volatile("s_waitcnt lgkmcnt(0)" ::: "memory");
    __builtin_amdgcn_s_barrier();
    __builtin_amdgcn_sched_barrier(0);
    {   // hs = W_hs @ hidden + b_hs
        float s = 0.f;
#pragma unroll 8
        for (int k2 = 0; k2 < 32; ++k2) {
            int kk = w*32 + k2;
            s = fmaf(g_WhsT[kk*64 + l], hid[kk], s);
        }
        part[w][l] = s;
    }
    asm volatile("s_waitcnt lgkmcnt(0)" ::: "memory");
    __builtin_amdgcn_s_barrier();
    __builtin_amdgcn_sched_barrier(0);
    if (tid < 64) {
        float v = b_hs[tid];
#pragma unroll
        for (int i = 0; i < 8; ++i) v += part[i][tid];
        hsL[tid] = v;
    }
    asm volatile("s_waitcnt lgkmcnt(0)" ::: "memory");
    __builtin_amdgcn_s_barrier();
    __builtin_amdgcn_sched_barrier(0);
    {   // qk = M2T^T @ hs + cvec
        float s = 0.f;
#pragma unroll
        for (int k2 = 0; k2 < 8; ++k2) {
            int kk = w*8 + k2;
            s = fmaf(g_M2T[kk*64 + l], hsL[kk], s);
        }
        part[w][l] = s;
    }
    asm volatile("s_waitcnt lgkmcnt(0)" ::: "memory");
    __builtin_amdgcn_s_barrier();
    __builtin_amdgcn_sched_barrier(0);
    if (tid < 64) {
        float v = g_cvec[tid];
#pragma unroll
        for (int i = 0; i < 8; ++i) v += part[i][tid];
        qkL[tid] = v;
    }
    asm volatile("s_waitcnt lgkmcnt(0)" ::: "memory");
    __builtin_amdgcn_s_barrier();
    __builtin_amdgcn_sched_barrier(0);
    embedW(0, Xe[0]);
    const f32x2 qkr = *(const f32x2*)&qkL[ebase0];
    const f32x2 hsd = *(const f32x2*)&hsL[ebase0];
    asm volatile("s_waitcnt vmcnt(2) lgkmcnt(0)" ::: "memory");   // tile0 staged
    __builtin_amdgcn_s_barrier();
    __builtin_amdgcn_sched_barrier(0);

    float m_run = -__builtin_inff(), l_run = 0.f;
    float ctxa[2] = {0.f, 0.f};
    float Eev[2][2];
    int hb = 0;

#pragma unroll 1
    for (int t = 0; t < 16; ++t) {
        const int base = t*32;
        const int cx = t & 1;

        // ---- phase 1: softmax(t-1) using spart[cx^1] + Eev registers ----
        if (t > 0) {
            const int c = l & 31;
            const float* spp = &spart[cx ^ 1][0][0];
            float s_p = spp[c];
#pragma unroll
            for (int i = 1; i < 8; ++i) s_p += spp[i*32 + c];
            float tm = s_p;
#pragma unroll
            for (int off = 1; off < 32; off <<= 1) tm = fmaxf(tm, __shfl_xor(tm, off, 64));
            float m_new = fmaxf(m_run, tm);
            float corr = ex2(m_run - m_new);
            float wp = ex2(s_p - m_new);
            l_run = fmaf(l_run, corr, wp);
            m_run = m_new;
            float wn0 = __shfl(wp, r, 64);
            float wn1 = __shfl(wp, 16 + r, 64);
#pragma unroll
            for (int mh = 0; mh < 2; ++mh)
                ctxa[mh] = fmaf(wn1, Eev[mh][1], fmaf(wn0, Eev[mh][0], ctxa[mh]*corr));
        }

        // ---- phase 2: MFMA + LSTM + spart[cx] write ----
        const float* HsC = &Hs[hb][0];
        const float* CsC = &Cs[hb][0];
        const unsigned short* XeC = &Xe[cx][0];
        f32x2 cpre[2];
#pragma unroll
        for (int nh = 0; nh < 2; ++nh) {
            const int p = 16*nh + r;
            cpre[nh] = *(const f32x2*)((const char*)CsC + p*256 +
                        ((ebase0*4) ^ ((p & 15) << 4)));
        }
        f32x4 acc[2][2];
#pragma unroll
        for (int mh = 0; mh < 2; ++mh)
#pragma unroll
            for (int nh = 0; nh < 2; ++nh) acc[mh][nh] = biasv[mh];
#pragma unroll
        for (int kh = 0; kh < 4; ++kh) {
            const bf16x8 Af0 = __builtin_bit_cast(bf16x8, Afr[0][kh]);
            const bf16x8 Af1 = __builtin_bit_cast(bf16x8, Afr[1][kh]);
#pragma unroll
            for (int nh = 0; nh < 2; ++nh) {
                const int p = 16*nh + r;
                bf16x8 Bf;
                if (kh < 2) {
                    Bf = *(const bf16x8*)((const char*)XeC + p*128 +
                          ((kh*64 + q*16) ^ ((p & 7) << 4)));
                } else {
                    const char* hbp = (const char*)HsC + p*256;
                    const int cbb = (kh - 2)*128 + q*32;
                    const int sw = (p & 15) << 4;
                    f32x4 f0 = *(const f32x4*)(hbp + (cbb ^ sw));
                    f32x4 f1 = *(const f32x4*)(hbp + ((cbb + 16) ^ sw));
                    Bf[0]=(__bf16)f0[0]; Bf[1]=(__bf16)f0[1]; Bf[2]=(__bf16)f0[2]; Bf[3]=(__bf16)f0[3];
                    Bf[4]=(__bf16)f1[0]; Bf[5]=(__bf16)f1[1]; Bf[6]=(__bf16)f1[2]; Bf[7]=(__bf16)f1[3];
                }
                acc[0][nh] = __builtin_amdgcn_mfma_f32_16x16x32_bf16(Af0, Bf, acc[0][nh], 0, 0, 0);
                acc[1][nh] = __builtin_amdgcn_mfma_f32_16x16x32_bf16(Af1, Bf, acc[1][nh], 0, 0, 0);
            }
        }
        float sp[2] = {0.f, 0.f};
#pragma unroll
        for (int nh = 0; nh < 2; ++nh) {
#pragma unroll
            for (int mh = 0; mh < 2; ++mh) {
                f32x4 g4 = acc[mh][nh];           // (yi, yf, yg, yo), pre-scaled
                float ea = ex2(g4[0]);
                float eg = ex2(g4[2]);
                float itg = (1.f - eg) * rcp_((1.f + ea)*(1.f + eg));   // sig(i)*tanh(g)
                float sf = rcp_(1.f + ex2(g4[1]));
                float cn = fmaf(sf, cpre[nh][mh], itg);
                float eo = ex2(g4[3]);
                float ec = ex2(-2.f*L2E*cn);
                float h = (1.f - ec) * rcp_((1.f + eo)*(1.f + ec));     // sig(o)*tanh(cn)
                h = (16*nh + r == b - base) ? hsd[mh] : h;
                Eev[mh][nh] = h;
                sp[nh] = fmaf(qkr[mh], h, sp[nh]);
            }
        }
#pragma unroll
        for (int nh = 0; nh < 2; ++nh) {
            float v = sp[nh];
            v += __shfl_xor(v, 16, 64);
            v += __shfl_xor(v, 32, 64);
            if (q == 0) spart[cx][w][16*nh + r] = v;
        }

        // ---- phase 3: stage(t+2), embed(t+1) ----
        if (t < 14) {
            const int hb2 = (hb == 0) ? 2 : hb - 1;   // (hb+2)%3
            stageT(h0r + (size_t)(t+2)*32*EE, &Hs[hb2][0]);
            stageT(c0r + (size_t)(t+2)*32*EE, &Cs[hb2][0]);
        }
        if (t < 15) embedW(base + 32, &Xe[cx ^ 1][0]);

        // ---- single barrier: spart/Xe visible, stage(t+1) landed ----
        if (t < 14) {
            asm volatile("s_waitcnt vmcnt(2) lgkmcnt(0)" ::: "memory");
        } else {
            asm volatile("s_waitcnt vmcnt(0) lgkmcnt(0)" ::: "memory");
        }
        __builtin_amdgcn_s_barrier();
        __builtin_amdgcn_sched_barrier(0);
        hb = (hb == 2) ? 0 : hb + 1;
    }

    // ---- final softmax (tile 15, spart[1]) ----
    {
        const int c = l & 31;
        const float* spp = &spart[1][0][0];
        float s_p = spp[c];
#pragma unroll
        for (int i = 1; i < 8; ++i) s_p += spp[i*32 + c];
        float tm = s_p;
#pragma unroll
        for (int off = 1; off < 32; off <<= 1) tm = fmaxf(tm, __shfl_xor(tm, off, 64));
        float m_new = fmaxf(m_run, tm);
        float corr = ex2(m_run - m_new);
        float wp = ex2(s_p - m_new);
        l_run = fmaf(l_run, corr, wp);
        m_run = m_new;
        float wn0 = __shfl(wp, r, 64);
        float wn1 = __shfl(wp, 16 + r, 64);
#pragma unroll
        for (int mh = 0; mh < 2; ++mh)
            ctxa[mh] = fmaf(wn1, Eev[mh][1], fmaf(wn0, Eev[mh][0], ctxa[mh]*corr));
    }

    // ---- epilogue: reduce, normalize, fused output projection ----
    float lred = l_run;
    lred += __shfl_xor(lred, 1, 64); lred += __shfl_xor(lred, 2, 64);
    lred += __shfl_xor(lred, 4, 64); lred += __shfl_xor(lred, 8, 64);
    lred += __shfl_xor(lred, 16, 64);
    const float inv = rcp_(lred);
#pragma unroll
    for (int mh = 0; mh < 2; ++mh) {
        float v = ctxa[mh];
        v += __shfl_xor(v, 1, 64); v += __shfl_xor(v, 2, 64);
        v += __shfl_xor(v, 4, 64); v += __shfl_xor(v, 8, 64);
        if (r == 0) ctxE[ebase0 + mh] = v * inv;
    }
    __syncthreads();
    if (tid < OUTD) {
        float sAcc = g_btot[tid];
        const float* wr2 = g_Wtot + tid*64;
        for (int k = 0; k < 64; ++k) sAcc = fmaf(wr2[k], ctxE[k], sAcc);
        out[b*OUTD + tid] = sAcc;
    }
}

extern "C" void kernel_launch(void* const* d_in, const int* in_sizes, int n_in,
                              void* d_out, int out_size, void* d_ws, size_t ws_size,
                              hipStream_t stream) {
    const float* hidden = (const float*)d_in[0];
    const float* obs1   = (const float*)d_in[1];
    const float* obs2   = (const float*)d_in[2];
    const float* h0     = (const float*)d_in[3];
    const float* c0     = (const float*)d_in[4];
    const float* W_s    = (const float*)d_in[5];
    const float* b_s    = (const float*)d_in[6];
    const float* W_v    = (const float*)d_in[7];
    const float* b_v    = (const float*)d_in[8];
    const float* W_hs   = (const float*)d_in[9];
    const float* b_hs   = (const float*)d_in[10];
    const float* W_ih   = (const float*)d_in[11];
    const float* b_ih   = (const float*)d_in[12];
    const float* W_hh   = (const float*)d_in[13];
    const float* b_hh   = (const float*)d_in[14];
    const float* Wq     = (const float*)d_in[15];
    const float* Wk     = (const float*)d_in[16];
    const float* Wv     = (const float*)d_in[17];
    const float* W_in   = (const float*)d_in[18];
    const float* b_in   = (const float*)d_in[19];
    const float* W_out  = (const float*)d_in[20];
    const float* b_out  = (const float*)d_in[21];
    const float* W_o    = (const float*)d_in[22];
    const float* b_o    = (const float*)d_in[23];

    prepW<<<dim3(12), dim3(256), 0, stream>>>(
        W_ih, b_ih, W_hh, b_hh, Wq, Wk, Wv, W_in, W_hs, W_s, b_s, W_v, b_v,
        b_in, W_out, b_out, W_o, b_o);
    row_kernel<<<dim3(NN), dim3(512), 0, stream>>>(
        hidden, b_hs, obs1, obs2, h0, c0, (float*)d_out);
}

// Round 9
// 68.262 us; speedup vs baseline: 3.0684x; 1.4310x over previous
//
#include <hip/hip_runtime.h>
#include <cstdint>

#define NN 512
#define EE 64
#define HIDD 256
#define OUTD 32
#define L2E 1.4426950408889634f

typedef __bf16 bf16x8 __attribute__((ext_vector_type(8)));
typedef __bf16 bf16x4 __attribute__((ext_vector_type(4)));
typedef float f32x4 __attribute__((ext_vector_type(4)));
typedef float f32x2 __attribute__((ext_vector_type(2)));

// -------- device-global scratch (fully rewritten every call; deterministic) --------
__device__ float g_WhsT[HIDD*EE];      // W_hs transposed [k][e]
__device__ uint4 g_Ag2[4096];          // bf16 A-frags, gate-scaled; idx = w:3|mh:1|kh:2|lane:6
__device__ float g_biasI[256];         // [e*4 + gate], gate-scaled
__device__ float g_embW[EE*4];         // per-e embed (a,b,bias,0)
__device__ float g_WqT[EE*EE];         // Wq transposed [k][e]
__device__ float g_Wq2T[EE*EE];        // W_in rows 0-63 transposed
__device__ float g_WvT[EE*EE];         // Wv transposed
__device__ float g_Wv2T[EE*EE];        // W_in rows 128-191 transposed
__device__ float g_WoutT[EE*EE];       // W_out transposed
__device__ float g_WoT[EE*OUTD];       // W_o transposed [k][o]

__device__ __forceinline__ float ex2(float x){ return __builtin_amdgcn_exp2f(x); }
__device__ __forceinline__ float rcp_(float x){ return __builtin_amdgcn_rcpf(x); }

// ---------------- prepW: packing + transposes only (NO matmuls), 13 blocks ----
__global__ __launch_bounds__(256) void prepW(
    const float* __restrict__ W_ih, const float* __restrict__ b_ih,
    const float* __restrict__ W_hh, const float* __restrict__ b_hh,
    const float* __restrict__ Wq, const float* __restrict__ Wv,
    const float* __restrict__ W_in, const float* __restrict__ W_hs,
    const float* __restrict__ W_s, const float* __restrict__ b_s,
    const float* __restrict__ W_v, const float* __restrict__ b_v,
    const float* __restrict__ W_out, const float* __restrict__ W_o)
{
    const int blk = blockIdx.x, tid = threadIdx.x;
    if (blk < 8) {
        // A-frags: wave w owns e in [8w,8w+8); e = 8w + 2*qq + mh; lane m = 4*qq+gate
#pragma unroll
        for (int ii = 0; ii < 2; ++ii) {
            int idx = blk*512 + ii*256 + tid;
            int w = idx >> 9, mh = (idx >> 8) & 1, kh = (idx >> 6) & 3, lane = idx & 63;
            int m = lane & 15, qq = m >> 2, gate = m & 3;
            int e = 8*w + 2*qq + mh;
            int o = gate*64 + e;
            int kb = kh*32 + (lane >> 4)*8;
            float sc = (gate == 2) ? (-2.f*L2E) : (-L2E);
            bf16x8 vv;
#pragma unroll
            for (int j = 0; j < 8; ++j) {
                int k = kb + j;
                float raw = (k < 64) ? W_ih[o*64 + k] : W_hh[o*64 + (k - 64)];
                vv[j] = (__bf16)(sc * raw);
            }
            g_Ag2[idx] = __builtin_bit_cast(uint4, vv);
        }
    } else if (blk == 8) {
        {
            int e = tid >> 2, gate = tid & 3, o = gate*64 + e;
            float sc = (gate == 2) ? (-2.f*L2E) : (-L2E);
            g_biasI[tid] = sc * (b_ih[o] + b_hh[o]);
        }
        if (tid < 64) {
            int e = tid;
            if (e < 32) {
                g_embW[e*4+0] = W_s[e*2]; g_embW[e*4+1] = W_s[e*2+1]; g_embW[e*4+2] = b_s[e];
            } else {
                g_embW[e*4+0] = 4.f*W_v[(e-32)*2]; g_embW[e*4+1] = 4.f*W_v[(e-32)*2+1]; g_embW[e*4+2] = b_v[e-32];
            }
            g_embW[e*4+3] = 0.f;
        }
    } else if (blk == 9) {
        // coalesced LDS-tiled transpose W_hs [64][256] -> g_WhsT [256][64]
        __shared__ float T[64][65];
        for (int kt = 0; kt < 4; ++kt) {
            __syncthreads();
#pragma unroll
            for (int i = 0; i < 16; ++i) {
                int row = i*4 + (tid >> 6);
                int col = tid & 63;
                T[col][row] = W_hs[row*256 + kt*64 + col];
            }
            __syncthreads();
#pragma unroll
            for (int i = 0; i < 16; ++i) {
                int krow = i*4 + (tid >> 6);
                int e = tid & 63;
                g_WhsT[(kt*64 + krow)*64 + e] = T[krow][e];
            }
        }
    } else {
        __shared__ float T[64][65];
        auto tr64 = [&](const float* src, float* dst) {
#pragma unroll
            for (int i = 0; i < 16; ++i) {
                int row = i*4 + (tid >> 6), col = tid & 63;
                T[col][row] = src[row*64 + col];
            }
            __syncthreads();
#pragma unroll
            for (int i = 0; i < 16; ++i) {
                int k = i*4 + (tid >> 6), e = tid & 63;
                dst[k*64 + e] = T[k][e];
            }
            __syncthreads();
        };
        if (blk == 10) {
            tr64(Wq, g_WqT);
            tr64(W_in, g_Wq2T);                 // rows 0-63 (q2)
        } else if (blk == 11) {
            tr64(Wv, g_WvT);
            tr64(W_in + 2*4096, g_Wv2T);        // rows 128-191 (v2)
        } else {
            tr64(W_out, g_WoutT);
            // W_o [32][64] -> g_WoT [64][32]
#pragma unroll
            for (int i = 0; i < 8; ++i) {
                int row = i*4 + (tid >> 6), col = tid & 63;
                T[col][row] = W_o[row*64 + col];
            }
            __syncthreads();
#pragma unroll
            for (int i = 0; i < 8; ++i) {
                int k = i*8 + (tid >> 5), o = tid & 31;
                g_WoT[k*32 + o] = T[k][o];
            }
        }
    }
}

// ---------------- row kernel: 512 blocks x 512 thr, full row, 16 tiles of 32,
// triple-buffered H/C, double-buffered Xe/spart, ONE barrier per tile ----------
__global__ __launch_bounds__(512, 4) void row_kernel(
    const float* __restrict__ hidden, const float* __restrict__ b_hs,
    const float* __restrict__ obs1, const float* __restrict__ obs2,
    const float* __restrict__ h0, const float* __restrict__ c0,
    const float* __restrict__ W_in, const float* __restrict__ Wk,
    const float* __restrict__ b_in, const float* __restrict__ b_out,
    const float* __restrict__ b_o, float* __restrict__ out)
{
    __shared__ __align__(16) float Hs[3][32*64];          // 24KB, swizzled 256B rows
    __shared__ __align__(16) float Cs[3][32*64];          // 24KB
    __shared__ __align__(16) unsigned short Xe[2][32*64]; // 8KB bf16, swizzled 128B rows
    __shared__ float spart[2][8][32];                     // 2KB
    __shared__ float2 obs1L[NN], obs2L[NN];               // 8KB
    __shared__ float hid[HIDD];
    __shared__ float part[8][64];
    __shared__ float hsL[64], qkL[64];
    __shared__ float vA[64], vB[64];
    __shared__ float ctxE[64];

    const int b = blockIdx.x, tid = threadIdx.x;
    const int w = tid >> 6, l = tid & 63;
    const int q = l >> 4, r = l & 15;
    const int ebase0 = 8*w + 2*q;
    const float* h0r = h0 + (size_t)b*NN*EE;
    const float* c0r = c0 + (size_t)b*NN*EE;

    // ---- staging: 1 global_load_lds (16B) per thread per buffer, pre-swizzled src ----
    auto stageT = [&](const float* gsrc, float* lbuf) {
        const int row = tid >> 4;                  // 0..31
        const int cb  = (tid & 15) * 16;
        const char* g = (const char*)gsrc + row*256 + (cb ^ ((row & 15) << 4));
        char* lp = (char*)lbuf + tid*16;
        __builtin_amdgcn_global_load_lds(
            (const __attribute__((address_space(1))) void*)g,
            (__attribute__((address_space(3))) void*)lp, 16, 0, 0);
    };

    // ---- shared matvec round: vout[e] = scale*(bias[e] + sum_k M[k*64+e]*vin[k]) ----
    auto matvecG = [&](const float* M, const float* vin, float* vout,
                       const float* bias, float scale) {
        float s = 0.f;
#pragma unroll
        for (int k2 = 0; k2 < 8; ++k2) {
            int kk = w*8 + k2;
            s = fmaf(M[kk*64 + l], vin[kk], s);
        }
        part[w][l] = s;
        asm volatile("s_waitcnt lgkmcnt(0)" ::: "memory");
        __builtin_amdgcn_s_barrier();
        if (tid < 64) {
            float v = bias ? bias[tid] : 0.f;
#pragma unroll
            for (int i = 0; i < 8; ++i) v += part[i][tid];
            vout[tid] = v * scale;
        }
        asm volatile("s_waitcnt lgkmcnt(0)" ::: "memory");
        __builtin_amdgcn_s_barrier();
    };

    // ---- register hoists ----
    uint4 Afr[2][4];
#pragma unroll
    for (int mh = 0; mh < 2; ++mh)
#pragma unroll
        for (int kh = 0; kh < 4; ++kh)
            Afr[mh][kh] = g_Ag2[w*512 + mh*256 + kh*64 + l];
    f32x4 biasv[2];
#pragma unroll
    for (int mh = 0; mh < 2; ++mh) {
        float4 t4 = *(const float4*)(g_biasI + (ebase0 + mh)*4);
        biasv[mh][0]=t4.x; biasv[mh][1]=t4.y; biasv[mh][2]=t4.z; biasv[mh][3]=t4.w;
    }
    float eA[4], eB[4], eC[4];
    {
        const int e0 = (tid & 15)*4;
#pragma unroll
        for (int i = 0; i < 4; ++i) {
            eA[i] = g_embW[(e0+i)*4+0]; eB[i] = g_embW[(e0+i)*4+1]; eC[i] = g_embW[(e0+i)*4+2];
        }
    }

    // ---- embed tile: thread = (p = tid>>4, e-quad tid&15), from LDS obs ----
    const float ob2x = obs2[b*2], ob2y = obs2[b*2+1];
    const float ob1x = obs1[b*2], ob1y = obs1[b*2+1];
    const float velbx = ob2x - ob1x, velby = ob2y - ob1y;
    auto embedW = [&](int jb, unsigned short* xe) {
        const int p = tid >> 4;
        const float2 o2 = obs2L[jb + p];
        const float2 o1 = obs1L[jb + p];
        const float u0s = o2.x - ob2x, u1s = o2.y - ob2y;
        const float u0v = (o2.x - o1.x) - velbx, u1v = (o2.y - o1.y) - velby;
        const bool sph = ((tid & 15) < 8);
        const float u0 = sph ? u0s : u0v, u1 = sph ? u1s : u1v;
        bf16x4 pk;
#pragma unroll
        for (int i = 0; i < 4; ++i)
            pk[i] = (__bf16)fmaxf(fmaf(eA[i], u0, fmaf(eB[i], u1, eC[i])), 0.f);
        *(bf16x4*)((char*)xe + p*128 + (((tid & 15)*8) ^ ((p & 7) << 4))) = pk;
    };

    // ---- prologue: issue stage(0),stage(1); obs/hid -> LDS; hs; qk-chain; embed(0) ----
    stageT(h0r, Hs[0]);
    stageT(c0r, Cs[0]);
    stageT(h0r + 32*EE, Hs[1]);
    stageT(c0r + 32*EE, Cs[1]);
    obs2L[tid] = ((const float2*)obs2)[tid];
    obs1L[tid] = ((const float2*)obs1)[tid];
    if (tid < HIDD) hid[tid] = hidden[b*HIDD + tid];
    asm volatile("s_waitcnt lgkmcnt(0)" ::: "memory");
    __builtin_amdgcn_s_barrier();
    __builtin_amdgcn_sched_barrier(0);
    {   // hs = W_hs @ hidden + b_hs
        float s = 0.f;
#pragma unroll 8
        for (int k2 = 0; k2 < 32; ++k2) {
            int kk = w*32 + k2;
            s = fmaf(g_WhsT[kk*64 + l], hid[kk], s);
        }
        part[w][l] = s;
    }
    asm volatile("s_waitcnt lgkmcnt(0)" ::: "memory");
    __builtin_amdgcn_s_barrier();
    if (tid < 64) {
        float v = b_hs[tid];
#pragma unroll
        for (int i = 0; i < 8; ++i) v += part[i][tid];
        hsL[tid] = v;
    }
    asm volatile("s_waitcnt lgkmcnt(0)" ::: "memory");
    __builtin_amdgcn_s_barrier();
    // qk chain: qk = (L2E/8) * Wk^T @ Wk2^T @ (Wq2 @ (Wq @ hs) + bq2)
    matvecG(g_WqT,       hsL, vA, nullptr, 1.f);
    matvecG(g_Wq2T,      vA,  vB, b_in,    1.f);
    matvecG(W_in + 4096, vB,  vA, nullptr, 1.f);
    matvecG(Wk,          vA,  qkL, nullptr, L2E*0.125f);
    embedW(0, Xe[0]);
    const f32x2 qkr = *(const f32x2*)&qkL[ebase0];
    const f32x2 hsd = *(const f32x2*)&hsL[ebase0];
    asm volatile("s_waitcnt vmcnt(2) lgkmcnt(0)" ::: "memory");   // tile0 staged
    __builtin_amdgcn_s_barrier();
    __builtin_amdgcn_sched_barrier(0);

    float m_run = -__builtin_inff(), l_run = 0.f;
    float ctxa[2] = {0.f, 0.f};
    float Eev[2][2];
    int hb = 0;

#pragma unroll 1
    for (int t = 0; t < 16; ++t) {
        const int base = t*32;
        const int cx = t & 1;

        // ---- phase 1: softmax(t-1) using spart[cx^1] + Eev registers ----
        if (t > 0) {
            const int c = l & 31;
            const float* spp = &spart[cx ^ 1][0][0];
            float s_p = spp[c];
#pragma unroll
            for (int i = 1; i < 8; ++i) s_p += spp[i*32 + c];
            float tm = s_p;
#pragma unroll
            for (int off = 1; off < 32; off <<= 1) tm = fmaxf(tm, __shfl_xor(tm, off, 64));
            float m_new = fmaxf(m_run, tm);
            float corr = ex2(m_run - m_new);
            float wp = ex2(s_p - m_new);
            l_run = fmaf(l_run, corr, wp);
            m_run = m_new;
            float wn0 = __shfl(wp, r, 64);
            float wn1 = __shfl(wp, 16 + r, 64);
#pragma unroll
            for (int mh = 0; mh < 2; ++mh)
                ctxa[mh] = fmaf(wn1, Eev[mh][1], fmaf(wn0, Eev[mh][0], ctxa[mh]*corr));
        }

        // ---- phase 2: MFMA + LSTM + spart[cx] write ----
        const float* HsC = &Hs[hb][0];
        const float* CsC = &Cs[hb][0];
        const unsigned short* XeC = &Xe[cx][0];
        f32x2 cpre[2];
#pragma unroll
        for (int nh = 0; nh < 2; ++nh) {
            const int p = 16*nh + r;
            cpre[nh] = *(const f32x2*)((const char*)CsC + p*256 +
                        ((ebase0*4) ^ ((p & 15) << 4)));
        }
        f32x4 acc[2][2];
#pragma unroll
        for (int mh = 0; mh < 2; ++mh)
#pragma unroll
            for (int nh = 0; nh < 2; ++nh) acc[mh][nh] = biasv[mh];
#pragma unroll
        for (int kh = 0; kh < 4; ++kh) {
            const bf16x8 Af0 = __builtin_bit_cast(bf16x8, Afr[0][kh]);
            const bf16x8 Af1 = __builtin_bit_cast(bf16x8, Afr[1][kh]);
#pragma unroll
            for (int nh = 0; nh < 2; ++nh) {
                const int p = 16*nh + r;
                bf16x8 Bf;
                if (kh < 2) {
                    Bf = *(const bf16x8*)((const char*)XeC + p*128 +
                          ((kh*64 + q*16) ^ ((p & 7) << 4)));
                } else {
                    const char* hbp = (const char*)HsC + p*256;
                    const int cbb = (kh - 2)*128 + q*32;
                    const int sw = (p & 15) << 4;
                    f32x4 f0 = *(const f32x4*)(hbp + (cbb ^ sw));
                    f32x4 f1 = *(const f32x4*)(hbp + ((cbb + 16) ^ sw));
                    Bf[0]=(__bf16)f0[0]; Bf[1]=(__bf16)f0[1]; Bf[2]=(__bf16)f0[2]; Bf[3]=(__bf16)f0[3];
                    Bf[4]=(__bf16)f1[0]; Bf[5]=(__bf16)f1[1]; Bf[6]=(__bf16)f1[2]; Bf[7]=(__bf16)f1[3];
                }
                acc[0][nh] = __builtin_amdgcn_mfma_f32_16x16x32_bf16(Af0, Bf, acc[0][nh], 0, 0, 0);
                acc[1][nh] = __builtin_amdgcn_mfma_f32_16x16x32_bf16(Af1, Bf, acc[1][nh], 0, 0, 0);
            }
        }
        float sp[2] = {0.f, 0.f};
#pragma unroll
        for (int nh = 0; nh < 2; ++nh) {
#pragma unroll
            for (int mh = 0; mh < 2; ++mh) {
                f32x4 g4 = acc[mh][nh];           // (yi, yf, yg, yo), pre-scaled
                float ea = ex2(g4[0]);
                float eg = ex2(g4[2]);
                float itg = (1.f - eg) * rcp_((1.f + ea)*(1.f + eg));   // sig(i)*tanh(g)
                float sf = rcp_(1.f + ex2(g4[1]));
                float cn = fmaf(sf, cpre[nh][mh], itg);
                float eo = ex2(g4[3]);
                float ec = ex2(-2.f*L2E*cn);
                float h = (1.f - ec) * rcp_((1.f + eo)*(1.f + ec));     // sig(o)*tanh(cn)
                h = (16*nh + r == b - base) ? hsd[mh] : h;
                Eev[mh][nh] = h;
                sp[nh] = fmaf(qkr[mh], h, sp[nh]);
            }
        }
#pragma unroll
        for (int nh = 0; nh < 2; ++nh) {
            float v = sp[nh];
            v += __shfl_xor(v, 16, 64);
            v += __shfl_xor(v, 32, 64);
            if (q == 0) spart[cx][w][16*nh + r] = v;
        }

        // ---- phase 3: stage(t+2), embed(t+1) ----
        if (t < 14) {
            const int hb2 = (hb == 0) ? 2 : hb - 1;   // (hb+2)%3
            stageT(h0r + (size_t)(t+2)*32*EE, &Hs[hb2][0]);
            stageT(c0r + (size_t)(t+2)*32*EE, &Cs[hb2][0]);
        }
        if (t < 15) embedW(base + 32, &Xe[cx ^ 1][0]);

        // ---- single barrier: spart/Xe visible, stage(t+1) landed ----
        if (t < 14) {
            asm volatile("s_waitcnt vmcnt(2) lgkmcnt(0)" ::: "memory");
        } else {
            asm volatile("s_waitcnt vmcnt(0) lgkmcnt(0)" ::: "memory");
        }
        __builtin_amdgcn_s_barrier();
        __builtin_amdgcn_sched_barrier(0);
        hb = (hb == 2) ? 0 : hb + 1;
    }

    // ---- final softmax (tile 15, spart[1]) ----
    {
        const int c = l & 31;
        const float* spp = &spart[1][0][0];
        float s_p = spp[c];
#pragma unroll
        for (int i = 1; i < 8; ++i) s_p += spp[i*32 + c];
        float tm = s_p;
#pragma unroll
        for (int off = 1; off < 32; off <<= 1) tm = fmaxf(tm, __shfl_xor(tm, off, 64));
        float m_new = fmaxf(m_run, tm);
        float corr = ex2(m_run - m_new);
        float wp = ex2(s_p - m_new);
        l_run = fmaf(l_run, corr, wp);
        m_run = m_new;
        float wn0 = __shfl(wp, r, 64);
        float wn1 = __shfl(wp, 16 + r, 64);
#pragma unroll
        for (int mh = 0; mh < 2; ++mh)
            ctxa[mh] = fmaf(wn1, Eev[mh][1], fmaf(wn0, Eev[mh][0], ctxa[mh]*corr));
    }

    // ---- epilogue: reduce, normalize, chained output projection ----
    float lred = l_run;
    lred += __shfl_xor(lred, 1, 64); lred += __shfl_xor(lred, 2, 64);
    lred += __shfl_xor(lred, 4, 64); lred += __shfl_xor(lred, 8, 64);
    lred += __shfl_xor(lred, 16, 64);
    const float inv = rcp_(lred);
#pragma unroll
    for (int mh = 0; mh < 2; ++mh) {
        float v = ctxa[mh];
        v += __shfl_xor(v, 1, 64); v += __shfl_xor(v, 2, 64);
        v += __shfl_xor(v, 4, 64); v += __shfl_xor(v, 8, 64);
        if (r == 0) ctxE[ebase0 + mh] = v * inv;
    }
    __syncthreads();
    // out = W_o @ (W_out @ (Wv2 @ (Wv @ ctxE) + bv2) + b_out) + b_o
    matvecG(g_WvT,   ctxE, vA, nullptr,    1.f);
    matvecG(g_Wv2T,  vA,   vB, b_in + 128, 1.f);
    matvecG(g_WoutT, vB,   vA, b_out,      1.f);
    {
        if (l < 32) {
            float s = 0.f;
#pragma unroll
            for (int k2 = 0; k2 < 8; ++k2) {
                int kk = w*8 + k2;
                s = fmaf(g_WoT[kk*32 + l], vA[kk], s);
            }
            part[w][l] = s;
        }
        __syncthreads();
        if (tid < 32) {
            float v = b_o[tid];
#pragma unroll
            for (int i = 0; i < 8; ++i) v += part[i][tid];
            out[b*OUTD + tid] = v;
        }
    }
}

extern "C" void kernel_launch(void* const* d_in, const int* in_sizes, int n_in,
                              void* d_out, int out_size, void* d_ws, size_t ws_size,
                              hipStream_t stream) {
    const float* hidden = (const float*)d_in[0];
    const float* obs1   = (const float*)d_in[1];
    const float* obs2   = (const float*)d_in[2];
    const float* h0     = (const float*)d_in[3];
    const float* c0     = (const float*)d_in[4];
    const float* W_s    = (const float*)d_in[5];
    const float* b_s    = (const float*)d_in[6];
    const float* W_v    = (const float*)d_in[7];
    const float* b_v    = (const float*)d_in[8];
    const float* W_hs   = (const float*)d_in[9];
    const float* b_hs   = (const float*)d_in[10];
    const float* W_ih   = (const float*)d_in[11];
    const float* b_ih   = (const float*)d_in[12];
    const float* W_hh   = (const float*)d_in[13];
    const float* b_hh   = (const float*)d_in[14];
    const float* Wq     = (const float*)d_in[15];
    const float* Wk     = (const float*)d_in[16];
    const float* Wv     = (const float*)d_in[17];
    const float* W_in   = (const float*)d_in[18];
    const float* b_in   = (const float*)d_in[19];
    const float* W_out  = (const float*)d_in[20];
    const float* b_out  = (const float*)d_in[21];
    const float* W_o    = (const float*)d_in[22];
    const float* b_o    = (const float*)d_in[23];

    prepW<<<dim3(13), dim3(256), 0, stream>>>(
        W_ih, b_ih, W_hh, b_hh, Wq, Wv, W_in, W_hs, W_s, b_s, W_v, b_v, W_out, W_o);
    row_kernel<<<dim3(NN), dim3(512), 0, stream>>>(
        hidden, b_hs, obs1, obs2, h0, c0, W_in, Wk, b_in, b_out, b_o, (float*)d_out);
}